// Round 18
// baseline (389.562 us; speedup 1.0000x reference)
//
#include <hip/hip_runtime.h>
#include <hip/hip_bf16.h>
#include <stdint.h>

// ---------------------------------------------------------------------------
// Decoder (teacher-forced, state never advances):
//   gates = x @ W_ih^T + (h0 @ W_hh^T + b_ih + b_hh)  (broadcast over t)
//   i,f,g,o = split(gates); c' = sig(f)*c0 + sig(i)*tanh(g); h' = sig(o)*tanh(c')
//   out = h' @ fc_w^T + fc_b
// Sizes: B=64, T=1024, D=513, H=512, 4H=2048.  M = B*T = 65536.
// R17: R16 config (best: 357.4us) + gemm1 K-pad elimination:
//   - x packed to 512 wide (not 544); K-loop 17 -> 16 tiles (-6% work).
//   - k=512 handled as a rank-1 epilogue update: gates += x[m,512]*W[p,512]
//     in f32 (prep writes sidecars x512f[65536], w512f[2048] packed-order).
//   Everything else byte-identical to R16 (prep fused, gemm1 R4 core +
//   cell epilogue, gemm2 R7 core + cell A-fetch + col-512 fusion).
// ---------------------------------------------------------------------------

typedef __bf16 bf16x8 __attribute__((ext_vector_type(8)));
typedef float f32x4 __attribute__((ext_vector_type(4)));

#define MFMA_BF16 __builtin_amdgcn_mfma_f32_16x16x32_bf16

__device__ __forceinline__ void gld16(const void* gptr, void* lptr) {
  __builtin_amdgcn_global_load_lds(
      (const __attribute__((address_space(1))) void*)gptr,
      (__attribute__((address_space(3))) void*)lptr, 16, 0, 0);
}

__device__ __forceinline__ float fsigm(float x) {
  x = fminf(fmaxf(x, -30.f), 30.f);
  return __frcp_rn(1.f + __expf(-x));
}
__device__ __forceinline__ float ftanh(float x) {
  x = fminf(fmaxf(x, -15.f), 15.f);
  const float e = __expf(2.f * x);
  return (e - 1.f) * __frcp_rn(e + 1.f);
}

// --------------------------- fused prep -------------------------------------
// Roles by blockIdx.x (small roles first so they overlap pack_x):
//   [0, 2048)        pack_wih (cols 0..511 -> wpk[p][512]; col 512 -> w512f[p])
//   [2048, 2688)     pack_fcw (rows 0..639, K 512, >=513 zero)
//   [2688, 35456)    hbias
//   [35456, 100992)  pack_x (cols 0..511 -> xbf[r][512]; col 512 -> x512f[r])
__global__ __launch_bounds__(256) void prep_kernel(
    const float* __restrict__ x, const float* __restrict__ Wih,
    const float* __restrict__ fcw, const float* __restrict__ h0,
    const float* __restrict__ Whh, const float* __restrict__ bih,
    const float* __restrict__ bhh, __bf16* __restrict__ xbf,
    __bf16* __restrict__ wpk, __bf16* __restrict__ fwbf,
    float* __restrict__ hbias, float* __restrict__ w512f,
    float* __restrict__ x512f) {
  const int bid = blockIdx.x;
  const int t = threadIdx.x;

  if (bid < 2048) {  // ---- pack_wih
    const int p = bid;
    const int g = (p >> 4) & 3;
    const int h = ((p >> 6) << 4) + (p & 15);
    const float* src = Wih + (size_t)(g * 512 + h) * 513;
    const int c = t * 2;  // 0..510
    union { __bf16 hh[2]; uint32_t u; } pk;
    pk.hh[0] = (__bf16)src[c];
    pk.hh[1] = (__bf16)src[c + 1];
    *(uint32_t*)&wpk[(size_t)p * 512 + c] = pk.u;
    if (t == 0) w512f[p] = src[512];
  } else if (bid < 2688) {  // ---- pack_fcw
    const int r = bid - 2048;
    const bool rv = r < 513;
    const float* src = fcw + (size_t)r * 512;
    const int c = t * 2;
    union { __bf16 hh[2]; uint32_t u; } pk;
    pk.hh[0] = (__bf16)(rv ? src[c] : 0.f);
    pk.hh[1] = (__bf16)(rv ? src[c + 1] : 0.f);
    *(uint32_t*)&fwbf[(size_t)r * 512 + c] = pk.u;
  } else if (bid < 35456) {  // ---- hbias
    const int hb_bid = bid - 2688;
    const int w = t >> 6, l = t & 63;
    const int b = hb_bid >> 9;
    const int g = ((hb_bid & 511) << 2) | w;
    const float* hr = h0 + b * 512;
    const float* wr = Whh + (size_t)g * 512;
    float s = 0.f;
#pragma unroll
    for (int h = 0; h < 512; h += 64) s = fmaf(hr[h + l], wr[h + l], s);
#pragma unroll
    for (int off = 32; off; off >>= 1) s += __shfl_down(s, off);
    if (l == 0) hbias[b * 2048 + g] = s + bih[g] + bhh[g];
  } else {  // ---- pack_x
    const int r = bid - 35456;
    const float* src = x + (size_t)r * 513;
    const int c = t * 2;  // 0..510
    union { __bf16 hh[2]; uint32_t u; } pk;
    pk.hh[0] = (__bf16)src[c];
    pk.hh[1] = (__bf16)src[c + 1];
    *(uint32_t*)&xbf[(size_t)r * 512 + c] = pk.u;
    if (t == 0) x512f[r] = src[512];
  }
}

// --------------------------- R4 core: 128x128, 4 waves ----------------------
// LDS: 3 buffers x (A 8KB + B 8KB) = 48KB. One barrier + vmcnt(4)/K-tile.
template <int NKT, int KSTR>
__device__ __forceinline__ void gemm_core4(
    const __bf16* __restrict__ A, const __bf16* __restrict__ B,
    size_t m0, int n0, char* lds, f32x4 (&acc)[4][4],
    int w, int l, int wm, int wc) {
  const int lr = l & 15, lq = l >> 4;
  const __bf16* ag = A + (m0 + w * 32 + lr) * KSTR + lq * 8;
  const __bf16* bg = B + (size_t)(n0 + w * 32 + lr) * KSTR + lq * 8;
  const int sdst = w * 2048;
  const int ra = wm * 4096 + l * 16;
  const int rbB = 8192 + wc * 4096 + l * 16;

#pragma unroll
  for (int p = 0; p < 2; ++p) {
    char* base = lds + p * 16384;
    gld16(ag + p * 32, base + sdst);
    gld16(ag + p * 32 + 16 * KSTR, base + sdst + 1024);
    gld16(bg + p * 32, base + 8192 + sdst);
    gld16(bg + p * 32 + 16 * KSTR, base + 8192 + sdst + 1024);
  }
  asm volatile("s_waitcnt vmcnt(4)" ::: "memory");
  __builtin_amdgcn_s_barrier();

  int rb = 0;
  for (int kt = 0; kt < NKT; ++kt) {
    char* rbase = lds + rb * 16384;
    if (kt + 2 < NKT) {
      char* wbase = lds + ((rb + 2) % 3) * 16384;
      const int kof = (kt + 2) * 32;
      gld16(ag + kof, wbase + sdst);
      gld16(ag + kof + 16 * KSTR, wbase + sdst + 1024);
      gld16(bg + kof, wbase + 8192 + sdst);
      gld16(bg + kof + 16 * KSTR, wbase + 8192 + sdst + 1024);
    }
    bf16x8 af[4], bq[4];
#pragma unroll
    for (int i = 0; i < 4; ++i)
      af[i] = *(const bf16x8*)(rbase + ra + i * 1024);
#pragma unroll
    for (int i = 0; i < 4; ++i)
      bq[i] = *(const bf16x8*)(rbase + rbB + i * 1024);
    __builtin_amdgcn_s_setprio(1);
#pragma unroll
    for (int mi = 0; mi < 4; ++mi)
#pragma unroll
      for (int ni = 0; ni < 4; ++ni)
        acc[mi][ni] = MFMA_BF16(af[mi], bq[ni], acc[mi][ni], 0, 0, 0);
    __builtin_amdgcn_s_setprio(0);
    if (kt + 2 < NKT) {
      asm volatile("s_waitcnt vmcnt(4)" ::: "memory");
    } else if (kt + 1 < NKT) {
      asm volatile("s_waitcnt vmcnt(0)" ::: "memory");
    }
    asm volatile("" ::: "memory");
    __builtin_amdgcn_s_barrier();
    rb = (rb == 2) ? 0 : rb + 1;
  }
}

// --------------------------- GEMM1 + LSTM cell ------------------------------
// A = xbf [65536 x 512], B = wpk [2048 x 512] gate-interleaved; K-loop 16
// tiles; k=512 added in the epilogue as a rank-1 f32 update.
// Output: hnew CELLS [4096 sm][16 kc] x 1KB; cell: lane=(kq<<4)|row, 8 k.
__global__ __launch_bounds__(256, 3) void gemm1_kernel(
    const __bf16* __restrict__ xbf, const __bf16* __restrict__ wpk,
    const float* __restrict__ hbias, const float* __restrict__ c0,
    const float* __restrict__ w512f, const float* __restrict__ x512f,
    __bf16* __restrict__ hnew) {
  const int t = threadIdx.x, w = t >> 6, l = t & 63;
  const int wm = w >> 1, wc = w & 1;
  const int bid = blockIdx.x;
  const int swz = (bid & 7) * 1024 + (bid >> 3);  // XCD-contiguous
  const size_t m0 = (size_t)(swz >> 4) << 7;
  const int n0 = (swz & 15) << 7;

  __shared__ __align__(16) char lds[49152];

  f32x4 acc[4][4];
#pragma unroll
  for (int mi = 0; mi < 4; ++mi)
#pragma unroll
    for (int ni = 0; ni < 4; ++ni) acc[mi][ni] = (f32x4){0.f, 0.f, 0.f, 0.f};

  gemm_core4<16, 512>(xbf, wpk, m0, n0, lds, acc, w, l, wm, wc);

  // lane's packed col p = n0 + wc*64 + ni*16 + lr -> gate = ni,
  // hcol = ((n0>>6)+wc)*16 + lr. All 4 gates lane-local.
  const int lr = l & 15, lq = l >> 4;
  const int hcol = (((n0 >> 6) + wc) << 4) + lr;
  const int b = (int)(m0 >> 10);
  const float hb0 = hbias[b * 2048 + hcol];
  const float hb1 = hbias[b * 2048 + 512 + hcol];
  const float hb2 = hbias[b * 2048 + 1024 + hcol];
  const float hb3 = hbias[b * 2048 + 1536 + hcol];
  const float c0v = c0[b * 512 + hcol];
  // k=512 rank-1 weights for this lane's 4 packed cols (gate = ni)
  const int pbase = n0 + wc * 64 + lr;
  const float w5_0 = w512f[pbase];
  const float w5_1 = w512f[pbase + 16];
  const float w5_2 = w512f[pbase + 32];
  const float w5_3 = w512f[pbase + 48];
  char* stg = lds;  // K-loop done (loop ends with barrier): LDS free
  const int l2b = (wc * 2 + (lr >> 3)) << 4;
  const int byt = (lr & 7) * 2;
#pragma unroll
  for (int mi = 0; mi < 4; ++mi) {
#pragma unroll
    for (int r = 0; r < 4; ++r) {
      const size_t m = m0 + wm * 64 + mi * 16 + lq * 4 + r;
      const float xv = x512f[m];
      const float gi = acc[mi][0][r] + hb0 + xv * w5_0;
      const float gf = acc[mi][1][r] + hb1 + xv * w5_1;
      const float gg = acc[mi][2][r] + hb2 + xv * w5_2;
      const float go = acc[mi][3][r] + hb3 + xv * w5_3;
      const float cn = fsigm(gf) * c0v + fsigm(gi) * ftanh(gg);
      const float hv = fsigm(go) * ftanh(cn);
      *(__bf16*)(stg + ((wm * 4 + mi) << 10) + (l2b + lq * 4 + r) * 16 + byt) =
          (__bf16)hv;
    }
  }
  __syncthreads();
  const int kc = n0 >> 7;
  char* hnc = (char*)hnew;
#pragma unroll
  for (int p = 0; p < 2; ++p) {
    const int cl = p * 4 + (t >> 6);
    const uint4 v = *(const uint4*)(stg + cl * 1024 + (t & 63) * 16);
    *(uint4*)(hnc + ((((m0 >> 4) + cl) << 4) + kc) * 1024 + (t & 63) * 16) = v;
  }
}

// --------------------------- R7 core, A from cells + col-512 fusion ---------
template <int NKT>
__device__ __forceinline__ void gemm_core8f(
    const char* __restrict__ Ac, const __bf16* __restrict__ B,
    size_t m0, int n0, char* lds, f32x4 (&acc)[4][4], float (&acc512)[4],
    bool do512, int wid, int l, int wm, int wc) {
  const int lr = l & 15, lq = l >> 4;
  const char* ag = Ac + (((m0 >> 4) + wid) << 14) + l * 16;   // subtile wid
  const char* ag2 = ag + (size_t)(8 << 14);                   // +128 rows
  const __bf16* bg = B + (size_t)(n0 + wid * 16 + lr) * 512 + lq * 8;
  const __bf16* w512p = B + (size_t)512 * 512 + lq * 8;       // fcw row 512
  const int sdA = wid << 10;
  const int sdB = 16384 + (wid << 10);
  const int ra = (wm << 12) + l * 16;
  const int rbB = 16384 + (wc << 12) + l * 16;

#pragma unroll
  for (int p = 0; p < 2; ++p) {
    char* base = lds + p * 24576;
    gld16(ag + p * 1024, base + sdA);
    gld16(ag2 + p * 1024, base + sdA + 8192);
    gld16(bg + p * 32, base + sdB);
  }
  asm volatile("s_waitcnt vmcnt(3)" ::: "memory");
  __builtin_amdgcn_s_barrier();

#pragma unroll
  for (int kt = 0; kt < NKT; ++kt) {
    char* rbase = lds + (kt % 3) * 24576;
    if (kt + 2 < NKT) {
      char* wbase = lds + ((kt + 2) % 3) * 24576;
      gld16(ag + (kt + 2) * 1024, wbase + sdA);
      gld16(ag2 + (kt + 2) * 1024, wbase + sdA + 8192);
      gld16(bg + (kt + 2) * 32, wbase + sdB);
    }
    bf16x8 af[4], bq[4];
#pragma unroll
    for (int i = 0; i < 4; ++i)
      af[i] = *(const bf16x8*)(rbase + ra + i * 1024);
#pragma unroll
    for (int i = 0; i < 4; ++i)
      bq[i] = *(const bf16x8*)(rbase + rbB + i * 1024);
    if (do512) {  // block- and wave-uniform branch
      const bf16x8 wv = *(const bf16x8*)(w512p + kt * 32);
#pragma unroll
      for (int mi = 0; mi < 4; ++mi)
#pragma unroll
        for (int j = 0; j < 8; ++j)
          acc512[mi] = fmaf((float)af[mi][j], (float)wv[j], acc512[mi]);
    }
    __builtin_amdgcn_s_setprio(1);
#pragma unroll
    for (int mi = 0; mi < 4; ++mi)
#pragma unroll
      for (int ni = 0; ni < 4; ++ni)
        acc[mi][ni] = MFMA_BF16(af[mi], bq[ni], acc[mi][ni], 0, 0, 0);
    __builtin_amdgcn_s_setprio(0);
    if (kt + 2 < NKT) {
      asm volatile("s_waitcnt vmcnt(3)" ::: "memory");
    } else if (kt + 1 < NKT) {
      asm volatile("s_waitcnt vmcnt(0)" ::: "memory");
    }
    asm volatile("" ::: "memory");
    __builtin_amdgcn_s_barrier();
  }
}

// --------------------------- GEMM2 + bias -----------------------------------
// A = hnew cells, B = fwbf. grid 1024 = 256 m-tiles x 4 n-tiles (cols 0..511).
// Col n=512 computed by ntile-0 blocks via the fused side-accumulation.
__global__ __launch_bounds__(512, 4) void gemm2_kernel(
    const char* __restrict__ hnc, const __bf16* __restrict__ fcw,
    const float* __restrict__ fcb, float* __restrict__ out) {
  const int t = threadIdx.x, wid = t >> 6, l = t & 63;
  const int wm = wid >> 1, wc = wid & 1;
  const int bid = blockIdx.x;
  const int swz = (bid & 7) * 128 + (bid >> 3);   // 1024 blocks
  const size_t m0 = (size_t)(swz >> 2) << 8;
  const int ntile = swz & 3;
  const int n0 = ntile << 7;
  const bool do512 = (ntile == 0) && (wc == 0);

  __shared__ __align__(16) char lds[73728];

  f32x4 acc[4][4];
  float acc512[4] = {0.f, 0.f, 0.f, 0.f};
#pragma unroll
  for (int mi = 0; mi < 4; ++mi)
#pragma unroll
    for (int ni = 0; ni < 4; ++ni) acc[mi][ni] = (f32x4){0.f, 0.f, 0.f, 0.f};

  gemm_core8f<16>(hnc, fcw, m0, n0, lds, acc, acc512, do512, wid, l, wm, wc);

  const int lr = l & 15, lq = l >> 4;
#pragma unroll
  for (int ni = 0; ni < 4; ++ni) {
    const int n = n0 + wc * 64 + ni * 16 + lr;
    const float bias = fcb[n];
#pragma unroll
    for (int mi = 0; mi < 4; ++mi) {
#pragma unroll
      for (int r = 0; r < 4; ++r) {
        const size_t m = m0 + wm * 64 + mi * 16 + lq * 4 + r;
        out[m * 513 + n] = acc[mi][ni][r] + bias;
      }
    }
  }
  if (do512) {  // reduce k-slices (lanes lr, 16+lr, 32+lr, 48+lr) and store
    const float b512 = fcb[512];
#pragma unroll
    for (int mi = 0; mi < 4; ++mi) {
      float s = acc512[mi];
      s += __shfl_down(s, 32);
      s += __shfl_down(s, 16);
      if (lq == 0) {
        const size_t m = m0 + (wm * 4 + mi) * 16 + lr;
        out[m * 513 + 512] = s + b512;
      }
    }
  }
}

// --------------------------- launch -----------------------------------------
extern "C" void kernel_launch(void* const* d_in, const int* in_sizes, int n_in,
                              void* d_out, int out_size, void* d_ws, size_t ws_size,
                              hipStream_t stream) {
  const float* x = (const float*)d_in[0];     // [64,1024,513]
  const float* h0 = (const float*)d_in[1];    // [1,64,512]
  const float* c0 = (const float*)d_in[2];    // [1,64,512]
  const float* Wih = (const float*)d_in[3];   // [2048,513]
  const float* Whh = (const float*)d_in[4];   // [2048,512]
  const float* bih = (const float*)d_in[5];   // [2048]
  const float* bhh = (const float*)d_in[6];   // [2048]
  const float* fcw = (const float*)d_in[7];   // [513,512]
  const float* fcb = (const float*)d_in[8];   // [513]
  float* out = (float*)d_out;                 // [64,1024,513]

  char* ws = (char*)d_ws;
  __bf16* xbf = (__bf16*)(ws);                 // 65536*512*2 = 67,108,864
  __bf16* wpk = (__bf16*)(ws + 67108864);      //  2048*512*2 =  2,097,152
  float* w512f = (float*)(ws + 69206016);      //      2048*4 =      8,192
  __bf16* fwbf = (__bf16*)(ws + 69214208);     //   640*512*2 =    655,360
  float* hb = (float*)(ws + 69869568);         //   64*2048*4 =    524,288
  float* x512f = (float*)(ws + 70393856);      //     65536*4 =    262,144
  char* hn = ws + 70656000;                    // cells: 4096*16*1024 = 67,108,864
  // total ws use: 137,764,864 bytes

  prep_kernel<<<100992, 256, 0, stream>>>(x, Wih, fcw, h0, Whh, bih, bhh,
                                          xbf, wpk, fwbf, hb, w512f, x512f);
  gemm1_kernel<<<8192, 256, 0, stream>>>(xbf, wpk, hb, c0, w512f, x512f,
                                         (__bf16*)hn);
  gemm2_kernel<<<1024, 512, 0, stream>>>(hn, fwbf, fcb, out);
}

// Round 19
// 339.126 us; speedup vs baseline: 1.1487x; 1.1487x over previous
//
#include <hip/hip_runtime.h>
#include <hip/hip_bf16.h>
#include <stdint.h>

// ---------------------------------------------------------------------------
// Decoder (teacher-forced, state never advances):
//   gates = x @ W_ih^T + (h0 @ W_hh^T + b_ih + b_hh)  (broadcast over t)
//   i,f,g,o = split(gates); c' = sig(f)*c0 + sig(i)*tanh(g); h' = sig(o)*tanh(c')
//   out = h' @ fc_w^T + fc_b
// Sizes: B=64, T=1024, D=513, H=512, 4H=2048.  M = B*T = 65536.
// R18: R17 (16-tile K loop + rank-1 k=512 epilogue) with the ROW STRIDE
//     RESTORED TO 544 elements (1088 B, non-power-of-2). R17's regression
//     (208->281us, HBM rate 540->390 GB/s) was L2 channel aliasing from the
//     1024 B power-of-2 stride (16-row staging hits every 4th channel).
//     Cols 512..543 of xbf/wpk are never read (K loop covers k<512 only).
//     Everything else byte-identical to R17.
// ---------------------------------------------------------------------------

typedef __bf16 bf16x8 __attribute__((ext_vector_type(8)));
typedef float f32x4 __attribute__((ext_vector_type(4)));

#define MFMA_BF16 __builtin_amdgcn_mfma_f32_16x16x32_bf16

__device__ __forceinline__ void gld16(const void* gptr, void* lptr) {
  __builtin_amdgcn_global_load_lds(
      (const __attribute__((address_space(1))) void*)gptr,
      (__attribute__((address_space(3))) void*)lptr, 16, 0, 0);
}

__device__ __forceinline__ float fsigm(float x) {
  x = fminf(fmaxf(x, -30.f), 30.f);
  return __frcp_rn(1.f + __expf(-x));
}
__device__ __forceinline__ float ftanh(float x) {
  x = fminf(fmaxf(x, -15.f), 15.f);
  const float e = __expf(2.f * x);
  return (e - 1.f) * __frcp_rn(e + 1.f);
}

// --------------------------- fused prep -------------------------------------
// Roles by blockIdx.x (small roles first so they overlap pack_x):
//   [0, 2048)        pack_wih (cols 0..511 -> wpk[p] stride 544; col512 -> w512f)
//   [2048, 2688)     pack_fcw (rows 0..639, K 512, >=513 zero)
//   [2688, 35456)    hbias
//   [35456, 100992)  pack_x (cols 0..511 -> xbf[r] stride 544; col512 -> x512f)
__global__ __launch_bounds__(256) void prep_kernel(
    const float* __restrict__ x, const float* __restrict__ Wih,
    const float* __restrict__ fcw, const float* __restrict__ h0,
    const float* __restrict__ Whh, const float* __restrict__ bih,
    const float* __restrict__ bhh, __bf16* __restrict__ xbf,
    __bf16* __restrict__ wpk, __bf16* __restrict__ fwbf,
    float* __restrict__ hbias, float* __restrict__ w512f,
    float* __restrict__ x512f) {
  const int bid = blockIdx.x;
  const int t = threadIdx.x;

  if (bid < 2048) {  // ---- pack_wih
    const int p = bid;
    const int g = (p >> 4) & 3;
    const int h = ((p >> 6) << 4) + (p & 15);
    const float* src = Wih + (size_t)(g * 512 + h) * 513;
    const int c = t * 2;  // 0..510
    union { __bf16 hh[2]; uint32_t u; } pk;
    pk.hh[0] = (__bf16)src[c];
    pk.hh[1] = (__bf16)src[c + 1];
    *(uint32_t*)&wpk[(size_t)p * 544 + c] = pk.u;
    if (t == 0) w512f[p] = src[512];
  } else if (bid < 2688) {  // ---- pack_fcw
    const int r = bid - 2048;
    const bool rv = r < 513;
    const float* src = fcw + (size_t)r * 512;
    const int c = t * 2;
    union { __bf16 hh[2]; uint32_t u; } pk;
    pk.hh[0] = (__bf16)(rv ? src[c] : 0.f);
    pk.hh[1] = (__bf16)(rv ? src[c + 1] : 0.f);
    *(uint32_t*)&fwbf[(size_t)r * 512 + c] = pk.u;
  } else if (bid < 35456) {  // ---- hbias
    const int hb_bid = bid - 2688;
    const int w = t >> 6, l = t & 63;
    const int b = hb_bid >> 9;
    const int g = ((hb_bid & 511) << 2) | w;
    const float* hr = h0 + b * 512;
    const float* wr = Whh + (size_t)g * 512;
    float s = 0.f;
#pragma unroll
    for (int h = 0; h < 512; h += 64) s = fmaf(hr[h + l], wr[h + l], s);
#pragma unroll
    for (int off = 32; off; off >>= 1) s += __shfl_down(s, off);
    if (l == 0) hbias[b * 2048 + g] = s + bih[g] + bhh[g];
  } else {  // ---- pack_x
    const int r = bid - 35456;
    const float* src = x + (size_t)r * 513;
    const int c = t * 2;  // 0..510
    union { __bf16 hh[2]; uint32_t u; } pk;
    pk.hh[0] = (__bf16)src[c];
    pk.hh[1] = (__bf16)src[c + 1];
    *(uint32_t*)&xbf[(size_t)r * 544 + c] = pk.u;
    if (t == 0) x512f[r] = src[512];
  }
}

// --------------------------- R4 core: 128x128, 4 waves ----------------------
// LDS: 3 buffers x (A 8KB + B 8KB) = 48KB. One barrier + vmcnt(4)/K-tile.
template <int NKT, int KSTR>
__device__ __forceinline__ void gemm_core4(
    const __bf16* __restrict__ A, const __bf16* __restrict__ B,
    size_t m0, int n0, char* lds, f32x4 (&acc)[4][4],
    int w, int l, int wm, int wc) {
  const int lr = l & 15, lq = l >> 4;
  const __bf16* ag = A + (m0 + w * 32 + lr) * KSTR + lq * 8;
  const __bf16* bg = B + (size_t)(n0 + w * 32 + lr) * KSTR + lq * 8;
  const int sdst = w * 2048;
  const int ra = wm * 4096 + l * 16;
  const int rbB = 8192 + wc * 4096 + l * 16;

#pragma unroll
  for (int p = 0; p < 2; ++p) {
    char* base = lds + p * 16384;
    gld16(ag + p * 32, base + sdst);
    gld16(ag + p * 32 + 16 * KSTR, base + sdst + 1024);
    gld16(bg + p * 32, base + 8192 + sdst);
    gld16(bg + p * 32 + 16 * KSTR, base + 8192 + sdst + 1024);
  }
  asm volatile("s_waitcnt vmcnt(4)" ::: "memory");
  __builtin_amdgcn_s_barrier();

  int rb = 0;
  for (int kt = 0; kt < NKT; ++kt) {
    char* rbase = lds + rb * 16384;
    if (kt + 2 < NKT) {
      char* wbase = lds + ((rb + 2) % 3) * 16384;
      const int kof = (kt + 2) * 32;
      gld16(ag + kof, wbase + sdst);
      gld16(ag + kof + 16 * KSTR, wbase + sdst + 1024);
      gld16(bg + kof, wbase + 8192 + sdst);
      gld16(bg + kof + 16 * KSTR, wbase + 8192 + sdst + 1024);
    }
    bf16x8 af[4], bq[4];
#pragma unroll
    for (int i = 0; i < 4; ++i)
      af[i] = *(const bf16x8*)(rbase + ra + i * 1024);
#pragma unroll
    for (int i = 0; i < 4; ++i)
      bq[i] = *(const bf16x8*)(rbase + rbB + i * 1024);
    __builtin_amdgcn_s_setprio(1);
#pragma unroll
    for (int mi = 0; mi < 4; ++mi)
#pragma unroll
      for (int ni = 0; ni < 4; ++ni)
        acc[mi][ni] = MFMA_BF16(af[mi], bq[ni], acc[mi][ni], 0, 0, 0);
    __builtin_amdgcn_s_setprio(0);
    if (kt + 2 < NKT) {
      asm volatile("s_waitcnt vmcnt(4)" ::: "memory");
    } else if (kt + 1 < NKT) {
      asm volatile("s_waitcnt vmcnt(0)" ::: "memory");
    }
    asm volatile("" ::: "memory");
    __builtin_amdgcn_s_barrier();
    rb = (rb == 2) ? 0 : rb + 1;
  }
}

// --------------------------- GEMM1 + LSTM cell ------------------------------
// A = xbf [65536 x 544-stride], B = wpk [2048 x 544-stride], K = 512
// (16 tiles); k=512 added in the epilogue as a rank-1 f32 update.
// Output: hnew CELLS [4096 sm][16 kc] x 1KB; cell: lane=(kq<<4)|row, 8 k.
__global__ __launch_bounds__(256, 3) void gemm1_kernel(
    const __bf16* __restrict__ xbf, const __bf16* __restrict__ wpk,
    const float* __restrict__ hbias, const float* __restrict__ c0,
    const float* __restrict__ w512f, const float* __restrict__ x512f,
    __bf16* __restrict__ hnew) {
  const int t = threadIdx.x, w = t >> 6, l = t & 63;
  const int wm = w >> 1, wc = w & 1;
  const int bid = blockIdx.x;
  const int swz = (bid & 7) * 1024 + (bid >> 3);  // XCD-contiguous
  const size_t m0 = (size_t)(swz >> 4) << 7;
  const int n0 = (swz & 15) << 7;

  __shared__ __align__(16) char lds[49152];

  f32x4 acc[4][4];
#pragma unroll
  for (int mi = 0; mi < 4; ++mi)
#pragma unroll
    for (int ni = 0; ni < 4; ++ni) acc[mi][ni] = (f32x4){0.f, 0.f, 0.f, 0.f};

  gemm_core4<16, 544>(xbf, wpk, m0, n0, lds, acc, w, l, wm, wc);

  // lane's packed col p = n0 + wc*64 + ni*16 + lr -> gate = ni,
  // hcol = ((n0>>6)+wc)*16 + lr. All 4 gates lane-local.
  const int lr = l & 15, lq = l >> 4;
  const int hcol = (((n0 >> 6) + wc) << 4) + lr;
  const int b = (int)(m0 >> 10);
  const float hb0 = hbias[b * 2048 + hcol];
  const float hb1 = hbias[b * 2048 + 512 + hcol];
  const float hb2 = hbias[b * 2048 + 1024 + hcol];
  const float hb3 = hbias[b * 2048 + 1536 + hcol];
  const float c0v = c0[b * 512 + hcol];
  // k=512 rank-1 weights for this lane's 4 packed cols (gate = ni)
  const int pbase = n0 + wc * 64 + lr;
  const float w5_0 = w512f[pbase];
  const float w5_1 = w512f[pbase + 16];
  const float w5_2 = w512f[pbase + 32];
  const float w5_3 = w512f[pbase + 48];
  char* stg = lds;  // K-loop done (loop ends with barrier): LDS free
  const int l2b = (wc * 2 + (lr >> 3)) << 4;
  const int byt = (lr & 7) * 2;
#pragma unroll
  for (int mi = 0; mi < 4; ++mi) {
#pragma unroll
    for (int r = 0; r < 4; ++r) {
      const size_t m = m0 + wm * 64 + mi * 16 + lq * 4 + r;
      const float xv = x512f[m];
      const float gi = acc[mi][0][r] + hb0 + xv * w5_0;
      const float gf = acc[mi][1][r] + hb1 + xv * w5_1;
      const float gg = acc[mi][2][r] + hb2 + xv * w5_2;
      const float go = acc[mi][3][r] + hb3 + xv * w5_3;
      const float cn = fsigm(gf) * c0v + fsigm(gi) * ftanh(gg);
      const float hv = fsigm(go) * ftanh(cn);
      *(__bf16*)(stg + ((wm * 4 + mi) << 10) + (l2b + lq * 4 + r) * 16 + byt) =
          (__bf16)hv;
    }
  }
  __syncthreads();
  const int kc = n0 >> 7;
  char* hnc = (char*)hnew;
#pragma unroll
  for (int p = 0; p < 2; ++p) {
    const int cl = p * 4 + (t >> 6);
    const uint4 v = *(const uint4*)(stg + cl * 1024 + (t & 63) * 16);
    *(uint4*)(hnc + ((((m0 >> 4) + cl) << 4) + kc) * 1024 + (t & 63) * 16) = v;
  }
}

// --------------------------- R7 core, A from cells + col-512 fusion ---------
template <int NKT>
__device__ __forceinline__ void gemm_core8f(
    const char* __restrict__ Ac, const __bf16* __restrict__ B,
    size_t m0, int n0, char* lds, f32x4 (&acc)[4][4], float (&acc512)[4],
    bool do512, int wid, int l, int wm, int wc) {
  const int lr = l & 15, lq = l >> 4;
  const char* ag = Ac + (((m0 >> 4) + wid) << 14) + l * 16;   // subtile wid
  const char* ag2 = ag + (size_t)(8 << 14);                   // +128 rows
  const __bf16* bg = B + (size_t)(n0 + wid * 16 + lr) * 512 + lq * 8;
  const __bf16* w512p = B + (size_t)512 * 512 + lq * 8;       // fcw row 512
  const int sdA = wid << 10;
  const int sdB = 16384 + (wid << 10);
  const int ra = (wm << 12) + l * 16;
  const int rbB = 16384 + (wc << 12) + l * 16;

#pragma unroll
  for (int p = 0; p < 2; ++p) {
    char* base = lds + p * 24576;
    gld16(ag + p * 1024, base + sdA);
    gld16(ag2 + p * 1024, base + sdA + 8192);
    gld16(bg + p * 32, base + sdB);
  }
  asm volatile("s_waitcnt vmcnt(3)" ::: "memory");
  __builtin_amdgcn_s_barrier();

#pragma unroll
  for (int kt = 0; kt < NKT; ++kt) {
    char* rbase = lds + (kt % 3) * 24576;
    if (kt + 2 < NKT) {
      char* wbase = lds + ((kt + 2) % 3) * 24576;
      gld16(ag + (kt + 2) * 1024, wbase + sdA);
      gld16(ag2 + (kt + 2) * 1024, wbase + sdA + 8192);
      gld16(bg + (kt + 2) * 32, wbase + sdB);
    }
    bf16x8 af[4], bq[4];
#pragma unroll
    for (int i = 0; i < 4; ++i)
      af[i] = *(const bf16x8*)(rbase + ra + i * 1024);
#pragma unroll
    for (int i = 0; i < 4; ++i)
      bq[i] = *(const bf16x8*)(rbase + rbB + i * 1024);
    if (do512) {  // block- and wave-uniform branch
      const bf16x8 wv = *(const bf16x8*)(w512p + kt * 32);
#pragma unroll
      for (int mi = 0; mi < 4; ++mi)
#pragma unroll
        for (int j = 0; j < 8; ++j)
          acc512[mi] = fmaf((float)af[mi][j], (float)wv[j], acc512[mi]);
    }
    __builtin_amdgcn_s_setprio(1);
#pragma unroll
    for (int mi = 0; mi < 4; ++mi)
#pragma unroll
      for (int ni = 0; ni < 4; ++ni)
        acc[mi][ni] = MFMA_BF16(af[mi], bq[ni], acc[mi][ni], 0, 0, 0);
    __builtin_amdgcn_s_setprio(0);
    if (kt + 2 < NKT) {
      asm volatile("s_waitcnt vmcnt(3)" ::: "memory");
    } else if (kt + 1 < NKT) {
      asm volatile("s_waitcnt vmcnt(0)" ::: "memory");
    }
    asm volatile("" ::: "memory");
    __builtin_amdgcn_s_barrier();
  }
}

// --------------------------- GEMM2 + bias -----------------------------------
// A = hnew cells, B = fwbf. grid 1024 = 256 m-tiles x 4 n-tiles (cols 0..511).
// Col n=512 computed by ntile-0 blocks via the fused side-accumulation.
__global__ __launch_bounds__(512, 4) void gemm2_kernel(
    const char* __restrict__ hnc, const __bf16* __restrict__ fcw,
    const float* __restrict__ fcb, float* __restrict__ out) {
  const int t = threadIdx.x, wid = t >> 6, l = t & 63;
  const int wm = wid >> 1, wc = wid & 1;
  const int bid = blockIdx.x;
  const int swz = (bid & 7) * 128 + (bid >> 3);   // 1024 blocks
  const size_t m0 = (size_t)(swz >> 2) << 8;
  const int ntile = swz & 3;
  const int n0 = ntile << 7;
  const bool do512 = (ntile == 0) && (wc == 0);

  __shared__ __align__(16) char lds[73728];

  f32x4 acc[4][4];
  float acc512[4] = {0.f, 0.f, 0.f, 0.f};
#pragma unroll
  for (int mi = 0; mi < 4; ++mi)
#pragma unroll
    for (int ni = 0; ni < 4; ++ni) acc[mi][ni] = (f32x4){0.f, 0.f, 0.f, 0.f};

  gemm_core8f<16>(hnc, fcw, m0, n0, lds, acc, acc512, do512, wid, l, wm, wc);

  const int lr = l & 15, lq = l >> 4;
#pragma unroll
  for (int ni = 0; ni < 4; ++ni) {
    const int n = n0 + wc * 64 + ni * 16 + lr;
    const float bias = fcb[n];
#pragma unroll
    for (int mi = 0; mi < 4; ++mi) {
#pragma unroll
      for (int r = 0; r < 4; ++r) {
        const size_t m = m0 + wm * 64 + mi * 16 + lq * 4 + r;
        out[m * 513 + n] = acc[mi][ni][r] + bias;
      }
    }
  }
  if (do512) {  // reduce k-slices (lanes lr, 16+lr, 32+lr, 48+lr) and store
    const float b512 = fcb[512];
#pragma unroll
    for (int mi = 0; mi < 4; ++mi) {
      float s = acc512[mi];
      s += __shfl_down(s, 32);
      s += __shfl_down(s, 16);
      if (lq == 0) {
        const size_t m = m0 + (wm * 4 + mi) * 16 + lr;
        out[m * 513 + 512] = s + b512;
      }
    }
  }
}

// --------------------------- launch -----------------------------------------
extern "C" void kernel_launch(void* const* d_in, const int* in_sizes, int n_in,
                              void* d_out, int out_size, void* d_ws, size_t ws_size,
                              hipStream_t stream) {
  const float* x = (const float*)d_in[0];     // [64,1024,513]
  const float* h0 = (const float*)d_in[1];    // [1,64,512]
  const float* c0 = (const float*)d_in[2];    // [1,64,512]
  const float* Wih = (const float*)d_in[3];   // [2048,513]
  const float* Whh = (const float*)d_in[4];   // [2048,512]
  const float* bih = (const float*)d_in[5];   // [2048]
  const float* bhh = (const float*)d_in[6];   // [2048]
  const float* fcw = (const float*)d_in[7];   // [513,512]
  const float* fcb = (const float*)d_in[8];   // [513]
  float* out = (float*)d_out;                 // [64,1024,513]

  char* ws = (char*)d_ws;
  __bf16* xbf = (__bf16*)(ws);                 // 65536*544*2 = 71,303,168
  __bf16* wpk = (__bf16*)(ws + 71303168);      //  2048*544*2 =  2,228,224
  float* w512f = (float*)(ws + 73531392);      //      2048*4 =      8,192
  __bf16* fwbf = (__bf16*)(ws + 73539584);     //   640*512*2 =    655,360
  float* hb = (float*)(ws + 74194944);         //   64*2048*4 =    524,288
  float* x512f = (float*)(ws + 74719232);      //     65536*4 =    262,144
  char* hn = ws + 74981376;                    // cells: 4096*16*1024 = 67,108,864
  // total ws use: 142,090,240 bytes

  prep_kernel<<<100992, 256, 0, stream>>>(x, Wih, fcw, h0, Whh, bih, bhh,
                                          xbf, wpk, fwbf, hb, w512f, x512f);
  gemm1_kernel<<<8192, 256, 0, stream>>>(xbf, wpk, hb, c0, w512f, x512f,
                                         (__bf16*)hn);
  gemm2_kernel<<<1024, 512, 0, stream>>>(hn, fwbf, fcb, out);
}

// Round 20
// 323.846 us; speedup vs baseline: 1.2029x; 1.0472x over previous
//
#include <hip/hip_runtime.h>
#include <hip/hip_bf16.h>
#include <stdint.h>

// ---------------------------------------------------------------------------
// Decoder (teacher-forced, state never advances):
//   gates = x @ W_ih^T + (h0 @ W_hh^T + b_ih + b_hh)  (broadcast over t)
//   i,f,g,o = split(gates); c' = sig(f)*c0 + sig(i)*tanh(g); h' = sig(o)*tanh(c')
//   out = h' @ fc_w^T + fc_b
// Sizes: B=64, T=1024, D=513, H=512, 4H=2048.  M = B*T = 65536.
// R19: R18 config (best: 339.1us) + tiled hbias role:
//   - hbias: 32768 blocks (wave per (b,g), Whh re-read 64x + h0 re-read
//     2048x = ~512 MB L2 traffic) -> 256 blocks, 8 Whh rows staged in 16KB
//     LDS once, each thread loops all 64 b (16 FMA vs L2-hot h0), width-32
//     shuffle reduce. Traffic ~36 MB. Still f32-exact.
//   Everything else byte-identical to R18 (stride-544 xbf/wpk, 16-tile
//   K-loop + rank-1 k=512 epilogue, cell hnew, gemm2 col-512 fusion).
// ---------------------------------------------------------------------------

typedef __bf16 bf16x8 __attribute__((ext_vector_type(8)));
typedef float f32x4 __attribute__((ext_vector_type(4)));

#define MFMA_BF16 __builtin_amdgcn_mfma_f32_16x16x32_bf16

__device__ __forceinline__ void gld16(const void* gptr, void* lptr) {
  __builtin_amdgcn_global_load_lds(
      (const __attribute__((address_space(1))) void*)gptr,
      (__attribute__((address_space(3))) void*)lptr, 16, 0, 0);
}

__device__ __forceinline__ float fsigm(float x) {
  x = fminf(fmaxf(x, -30.f), 30.f);
  return __frcp_rn(1.f + __expf(-x));
}
__device__ __forceinline__ float ftanh(float x) {
  x = fminf(fmaxf(x, -15.f), 15.f);
  const float e = __expf(2.f * x);
  return (e - 1.f) * __frcp_rn(e + 1.f);
}

// --------------------------- fused prep -------------------------------------
// Roles by blockIdx.x (long-running hbias first):
//   [0, 256)         hbias tiled: block owns 8 g; 8 Whh rows in LDS; loops 64 b
//   [256, 2304)      pack_wih (cols 0..511 -> wpk stride 544; col512 -> w512f)
//   [2304, 2944)     pack_fcw (rows 0..639, K 512, >=513 zero)
//   [2944, 68480)    pack_x (cols 0..511 -> xbf stride 544; col512 -> x512f)
__global__ __launch_bounds__(256) void prep_kernel(
    const float* __restrict__ x, const float* __restrict__ Wih,
    const float* __restrict__ fcw, const float* __restrict__ h0,
    const float* __restrict__ Whh, const float* __restrict__ bih,
    const float* __restrict__ bhh, __bf16* __restrict__ xbf,
    __bf16* __restrict__ wpk, __bf16* __restrict__ fwbf,
    float* __restrict__ hbias, float* __restrict__ w512f,
    float* __restrict__ x512f) {
  __shared__ float wsm[8][512];  // 16KB; only the hbias role touches it
  const int bid = blockIdx.x;
  const int t = threadIdx.x;

  if (bid < 256) {  // ---- hbias (tiled GEMV, f32-exact)
    const int g0 = bid * 8;
    for (int i = t; i < 8 * 512; i += 256)
      wsm[i >> 9][i & 511] = Whh[(size_t)(g0 + (i >> 9)) * 512 + (i & 511)];
    __syncthreads();
    const int g = t >> 5;   // 0..7
    const int kg = t & 31;  // 0..31
    const float bsum = bih[g0 + g] + bhh[g0 + g];
    for (int b = 0; b < 64; ++b) {
      const float* hr = h0 + b * 512 + kg;
      float s = 0.f;
#pragma unroll
      for (int q = 0; q < 16; ++q)
        s = fmaf(hr[32 * q], wsm[g][kg + 32 * q], s);
#pragma unroll
      for (int off = 16; off; off >>= 1) s += __shfl_down(s, off, 32);
      if (kg == 0) hbias[b * 2048 + g0 + g] = s + bsum;
    }
  } else if (bid < 2304) {  // ---- pack_wih
    const int p = bid - 256;
    const int g = (p >> 4) & 3;
    const int h = ((p >> 6) << 4) + (p & 15);
    const float* src = Wih + (size_t)(g * 512 + h) * 513;
    const int c = t * 2;  // 0..510
    union { __bf16 hh[2]; uint32_t u; } pk;
    pk.hh[0] = (__bf16)src[c];
    pk.hh[1] = (__bf16)src[c + 1];
    *(uint32_t*)&wpk[(size_t)p * 544 + c] = pk.u;
    if (t == 0) w512f[p] = src[512];
  } else if (bid < 2944) {  // ---- pack_fcw
    const int r = bid - 2304;
    const bool rv = r < 513;
    const float* src = fcw + (size_t)r * 512;
    const int c = t * 2;
    union { __bf16 hh[2]; uint32_t u; } pk;
    pk.hh[0] = (__bf16)(rv ? src[c] : 0.f);
    pk.hh[1] = (__bf16)(rv ? src[c + 1] : 0.f);
    *(uint32_t*)&fwbf[(size_t)r * 512 + c] = pk.u;
  } else {  // ---- pack_x
    const int r = bid - 2944;
    const float* src = x + (size_t)r * 513;
    const int c = t * 2;  // 0..510
    union { __bf16 hh[2]; uint32_t u; } pk;
    pk.hh[0] = (__bf16)src[c];
    pk.hh[1] = (__bf16)src[c + 1];
    *(uint32_t*)&xbf[(size_t)r * 544 + c] = pk.u;
    if (t == 0) x512f[r] = src[512];
  }
}

// --------------------------- R4 core: 128x128, 4 waves ----------------------
// LDS: 3 buffers x (A 8KB + B 8KB) = 48KB. One barrier + vmcnt(4)/K-tile.
template <int NKT, int KSTR>
__device__ __forceinline__ void gemm_core4(
    const __bf16* __restrict__ A, const __bf16* __restrict__ B,
    size_t m0, int n0, char* lds, f32x4 (&acc)[4][4],
    int w, int l, int wm, int wc) {
  const int lr = l & 15, lq = l >> 4;
  const __bf16* ag = A + (m0 + w * 32 + lr) * KSTR + lq * 8;
  const __bf16* bg = B + (size_t)(n0 + w * 32 + lr) * KSTR + lq * 8;
  const int sdst = w * 2048;
  const int ra = wm * 4096 + l * 16;
  const int rbB = 8192 + wc * 4096 + l * 16;

#pragma unroll
  for (int p = 0; p < 2; ++p) {
    char* base = lds + p * 16384;
    gld16(ag + p * 32, base + sdst);
    gld16(ag + p * 32 + 16 * KSTR, base + sdst + 1024);
    gld16(bg + p * 32, base + 8192 + sdst);
    gld16(bg + p * 32 + 16 * KSTR, base + 8192 + sdst + 1024);
  }
  asm volatile("s_waitcnt vmcnt(4)" ::: "memory");
  __builtin_amdgcn_s_barrier();

  int rb = 0;
  for (int kt = 0; kt < NKT; ++kt) {
    char* rbase = lds + rb * 16384;
    if (kt + 2 < NKT) {
      char* wbase = lds + ((rb + 2) % 3) * 16384;
      const int kof = (kt + 2) * 32;
      gld16(ag + kof, wbase + sdst);
      gld16(ag + kof + 16 * KSTR, wbase + sdst + 1024);
      gld16(bg + kof, wbase + 8192 + sdst);
      gld16(bg + kof + 16 * KSTR, wbase + 8192 + sdst + 1024);
    }
    bf16x8 af[4], bq[4];
#pragma unroll
    for (int i = 0; i < 4; ++i)
      af[i] = *(const bf16x8*)(rbase + ra + i * 1024);
#pragma unroll
    for (int i = 0; i < 4; ++i)
      bq[i] = *(const bf16x8*)(rbase + rbB + i * 1024);
    __builtin_amdgcn_s_setprio(1);
#pragma unroll
    for (int mi = 0; mi < 4; ++mi)
#pragma unroll
      for (int ni = 0; ni < 4; ++ni)
        acc[mi][ni] = MFMA_BF16(af[mi], bq[ni], acc[mi][ni], 0, 0, 0);
    __builtin_amdgcn_s_setprio(0);
    if (kt + 2 < NKT) {
      asm volatile("s_waitcnt vmcnt(4)" ::: "memory");
    } else if (kt + 1 < NKT) {
      asm volatile("s_waitcnt vmcnt(0)" ::: "memory");
    }
    asm volatile("" ::: "memory");
    __builtin_amdgcn_s_barrier();
    rb = (rb == 2) ? 0 : rb + 1;
  }
}

// --------------------------- GEMM1 + LSTM cell ------------------------------
// A = xbf [65536 x 544-stride], B = wpk [2048 x 544-stride], K = 512
// (16 tiles); k=512 added in the epilogue as a rank-1 f32 update.
// Output: hnew CELLS [4096 sm][16 kc] x 1KB; cell: lane=(kq<<4)|row, 8 k.
__global__ __launch_bounds__(256, 3) void gemm1_kernel(
    const __bf16* __restrict__ xbf, const __bf16* __restrict__ wpk,
    const float* __restrict__ hbias, const float* __restrict__ c0,
    const float* __restrict__ w512f, const float* __restrict__ x512f,
    __bf16* __restrict__ hnew) {
  const int t = threadIdx.x, w = t >> 6, l = t & 63;
  const int wm = w >> 1, wc = w & 1;
  const int bid = blockIdx.x;
  const int swz = (bid & 7) * 1024 + (bid >> 3);  // XCD-contiguous
  const size_t m0 = (size_t)(swz >> 4) << 7;
  const int n0 = (swz & 15) << 7;

  __shared__ __align__(16) char lds[49152];

  f32x4 acc[4][4];
#pragma unroll
  for (int mi = 0; mi < 4; ++mi)
#pragma unroll
    for (int ni = 0; ni < 4; ++ni) acc[mi][ni] = (f32x4){0.f, 0.f, 0.f, 0.f};

  gemm_core4<16, 544>(xbf, wpk, m0, n0, lds, acc, w, l, wm, wc);

  // lane's packed col p = n0 + wc*64 + ni*16 + lr -> gate = ni,
  // hcol = ((n0>>6)+wc)*16 + lr. All 4 gates lane-local.
  const int lr = l & 15, lq = l >> 4;
  const int hcol = (((n0 >> 6) + wc) << 4) + lr;
  const int b = (int)(m0 >> 10);
  const float hb0 = hbias[b * 2048 + hcol];
  const float hb1 = hbias[b * 2048 + 512 + hcol];
  const float hb2 = hbias[b * 2048 + 1024 + hcol];
  const float hb3 = hbias[b * 2048 + 1536 + hcol];
  const float c0v = c0[b * 512 + hcol];
  // k=512 rank-1 weights for this lane's 4 packed cols (gate = ni)
  const int pbase = n0 + wc * 64 + lr;
  const float w5_0 = w512f[pbase];
  const float w5_1 = w512f[pbase + 16];
  const float w5_2 = w512f[pbase + 32];
  const float w5_3 = w512f[pbase + 48];
  char* stg = lds;  // K-loop done (loop ends with barrier): LDS free
  const int l2b = (wc * 2 + (lr >> 3)) << 4;
  const int byt = (lr & 7) * 2;
#pragma unroll
  for (int mi = 0; mi < 4; ++mi) {
#pragma unroll
    for (int r = 0; r < 4; ++r) {
      const size_t m = m0 + wm * 64 + mi * 16 + lq * 4 + r;
      const float xv = x512f[m];
      const float gi = acc[mi][0][r] + hb0 + xv * w5_0;
      const float gf = acc[mi][1][r] + hb1 + xv * w5_1;
      const float gg = acc[mi][2][r] + hb2 + xv * w5_2;
      const float go = acc[mi][3][r] + hb3 + xv * w5_3;
      const float cn = fsigm(gf) * c0v + fsigm(gi) * ftanh(gg);
      const float hv = fsigm(go) * ftanh(cn);
      *(__bf16*)(stg + ((wm * 4 + mi) << 10) + (l2b + lq * 4 + r) * 16 + byt) =
          (__bf16)hv;
    }
  }
  __syncthreads();
  const int kc = n0 >> 7;
  char* hnc = (char*)hnew;
#pragma unroll
  for (int p = 0; p < 2; ++p) {
    const int cl = p * 4 + (t >> 6);
    const uint4 v = *(const uint4*)(stg + cl * 1024 + (t & 63) * 16);
    *(uint4*)(hnc + ((((m0 >> 4) + cl) << 4) + kc) * 1024 + (t & 63) * 16) = v;
  }
}

// --------------------------- R7 core, A from cells + col-512 fusion ---------
template <int NKT>
__device__ __forceinline__ void gemm_core8f(
    const char* __restrict__ Ac, const __bf16* __restrict__ B,
    size_t m0, int n0, char* lds, f32x4 (&acc)[4][4], float (&acc512)[4],
    bool do512, int wid, int l, int wm, int wc) {
  const int lr = l & 15, lq = l >> 4;
  const char* ag = Ac + (((m0 >> 4) + wid) << 14) + l * 16;   // subtile wid
  const char* ag2 = ag + (size_t)(8 << 14);                   // +128 rows
  const __bf16* bg = B + (size_t)(n0 + wid * 16 + lr) * 512 + lq * 8;
  const __bf16* w512p = B + (size_t)512 * 512 + lq * 8;       // fcw row 512
  const int sdA = wid << 10;
  const int sdB = 16384 + (wid << 10);
  const int ra = (wm << 12) + l * 16;
  const int rbB = 16384 + (wc << 12) + l * 16;

#pragma unroll
  for (int p = 0; p < 2; ++p) {
    char* base = lds + p * 24576;
    gld16(ag + p * 1024, base + sdA);
    gld16(ag2 + p * 1024, base + sdA + 8192);
    gld16(bg + p * 32, base + sdB);
  }
  asm volatile("s_waitcnt vmcnt(3)" ::: "memory");
  __builtin_amdgcn_s_barrier();

#pragma unroll
  for (int kt = 0; kt < NKT; ++kt) {
    char* rbase = lds + (kt % 3) * 24576;
    if (kt + 2 < NKT) {
      char* wbase = lds + ((kt + 2) % 3) * 24576;
      gld16(ag + (kt + 2) * 1024, wbase + sdA);
      gld16(ag2 + (kt + 2) * 1024, wbase + sdA + 8192);
      gld16(bg + (kt + 2) * 32, wbase + sdB);
    }
    bf16x8 af[4], bq[4];
#pragma unroll
    for (int i = 0; i < 4; ++i)
      af[i] = *(const bf16x8*)(rbase + ra + i * 1024);
#pragma unroll
    for (int i = 0; i < 4; ++i)
      bq[i] = *(const bf16x8*)(rbase + rbB + i * 1024);
    if (do512) {  // block- and wave-uniform branch
      const bf16x8 wv = *(const bf16x8*)(w512p + kt * 32);
#pragma unroll
      for (int mi = 0; mi < 4; ++mi)
#pragma unroll
        for (int j = 0; j < 8; ++j)
          acc512[mi] = fmaf((float)af[mi][j], (float)wv[j], acc512[mi]);
    }
    __builtin_amdgcn_s_setprio(1);
#pragma unroll
    for (int mi = 0; mi < 4; ++mi)
#pragma unroll
      for (int ni = 0; ni < 4; ++ni)
        acc[mi][ni] = MFMA_BF16(af[mi], bq[ni], acc[mi][ni], 0, 0, 0);
    __builtin_amdgcn_s_setprio(0);
    if (kt + 2 < NKT) {
      asm volatile("s_waitcnt vmcnt(3)" ::: "memory");
    } else if (kt + 1 < NKT) {
      asm volatile("s_waitcnt vmcnt(0)" ::: "memory");
    }
    asm volatile("" ::: "memory");
    __builtin_amdgcn_s_barrier();
  }
}

// --------------------------- GEMM2 + bias -----------------------------------
// A = hnew cells, B = fwbf. grid 1024 = 256 m-tiles x 4 n-tiles (cols 0..511).
// Col n=512 computed by ntile-0 blocks via the fused side-accumulation.
__global__ __launch_bounds__(512, 4) void gemm2_kernel(
    const char* __restrict__ hnc, const __bf16* __restrict__ fcw,
    const float* __restrict__ fcb, float* __restrict__ out) {
  const int t = threadIdx.x, wid = t >> 6, l = t & 63;
  const int wm = wid >> 1, wc = wid & 1;
  const int bid = blockIdx.x;
  const int swz = (bid & 7) * 128 + (bid >> 3);   // 1024 blocks
  const size_t m0 = (size_t)(swz >> 2) << 8;
  const int ntile = swz & 3;
  const int n0 = ntile << 7;
  const bool do512 = (ntile == 0) && (wc == 0);

  __shared__ __align__(16) char lds[73728];

  f32x4 acc[4][4];
  float acc512[4] = {0.f, 0.f, 0.f, 0.f};
#pragma unroll
  for (int mi = 0; mi < 4; ++mi)
#pragma unroll
    for (int ni = 0; ni < 4; ++ni) acc[mi][ni] = (f32x4){0.f, 0.f, 0.f, 0.f};

  gemm_core8f<16>(hnc, fcw, m0, n0, lds, acc, acc512, do512, wid, l, wm, wc);

  const int lr = l & 15, lq = l >> 4;
#pragma unroll
  for (int ni = 0; ni < 4; ++ni) {
    const int n = n0 + wc * 64 + ni * 16 + lr;
    const float bias = fcb[n];
#pragma unroll
    for (int mi = 0; mi < 4; ++mi) {
#pragma unroll
      for (int r = 0; r < 4; ++r) {
        const size_t m = m0 + wm * 64 + mi * 16 + lq * 4 + r;
        out[m * 513 + n] = acc[mi][ni][r] + bias;
      }
    }
  }
  if (do512) {  // reduce k-slices (lanes lr, 16+lr, 32+lr, 48+lr) and store
    const float b512 = fcb[512];
#pragma unroll
    for (int mi = 0; mi < 4; ++mi) {
      float s = acc512[mi];
      s += __shfl_down(s, 32);
      s += __shfl_down(s, 16);
      if (lq == 0) {
        const size_t m = m0 + (wm * 4 + mi) * 16 + lr;
        out[m * 513 + 512] = s + b512;
      }
    }
  }
}

// --------------------------- launch -----------------------------------------
extern "C" void kernel_launch(void* const* d_in, const int* in_sizes, int n_in,
                              void* d_out, int out_size, void* d_ws, size_t ws_size,
                              hipStream_t stream) {
  const float* x = (const float*)d_in[0];     // [64,1024,513]
  const float* h0 = (const float*)d_in[1];    // [1,64,512]
  const float* c0 = (const float*)d_in[2];    // [1,64,512]
  const float* Wih = (const float*)d_in[3];   // [2048,513]
  const float* Whh = (const float*)d_in[4];   // [2048,512]
  const float* bih = (const float*)d_in[5];   // [2048]
  const float* bhh = (const float*)d_in[6];   // [2048]
  const float* fcw = (const float*)d_in[7];   // [513,512]
  const float* fcb = (const float*)d_in[8];   // [513]
  float* out = (float*)d_out;                 // [64,1024,513]

  char* ws = (char*)d_ws;
  __bf16* xbf = (__bf16*)(ws);                 // 65536*544*2 = 71,303,168
  __bf16* wpk = (__bf16*)(ws + 71303168);      //  2048*544*2 =  2,228,224
  float* w512f = (float*)(ws + 73531392);      //      2048*4 =      8,192
  __bf16* fwbf = (__bf16*)(ws + 73539584);     //   640*512*2 =    655,360
  float* hb = (float*)(ws + 74194944);         //   64*2048*4 =    524,288
  float* x512f = (float*)(ws + 74719232);      //     65536*4 =    262,144
  char* hn = ws + 74981376;                    // cells: 4096*16*1024 = 67,108,864
  // total ws use: 142,090,240 bytes

  prep_kernel<<<68480, 256, 0, stream>>>(x, Wih, fcw, h0, Whh, bih, bhh,
                                         xbf, wpk, fwbf, hb, w512f, x512f);
  gemm1_kernel<<<8192, 256, 0, stream>>>(xbf, wpk, hb, c0, w512f, x512f,
                                         (__bf16*)hn);
  gemm2_kernel<<<1024, 512, 0, stream>>>(hn, fwbf, fcb, out);
}

// Round 21
// 298.276 us; speedup vs baseline: 1.3060x; 1.0857x over previous
//
#include <hip/hip_runtime.h>
#include <hip/hip_bf16.h>
#include <stdint.h>

// ---------------------------------------------------------------------------
// Decoder (teacher-forced, state never advances):
//   gates = x @ W_ih^T + (h0 @ W_hh^T + b_ih + b_hh)  (broadcast over t)
//   i,f,g,o = split(gates); c' = sig(f)*c0 + sig(i)*tanh(g); h' = sig(o)*tanh(c')
//   out = h' @ fc_w^T + fc_b
// Sizes: B=64, T=1024, D=513, H=512, 4H=2048.  M = B*T = 65536.
// R20: R19 config (best: 323.8us) + gemm1 epilogue trans-pipe diet:
//   - sigmoid/tanh via raw v_rcp_f32 (__builtin_amdgcn_rcpf, 1 trans op)
//     instead of correctly-rounded __frcp_rn (multi-instr Newton chain);
//     clamps dropped (IEEE inf propagation gives exact limits: exp->inf =>
//     rcp->0 => sigmoid->0 / tanh->1; inputs finite).
//   - x512f epilogue loads vectorized: 16 scalar -> 4x float4 (r consecutive).
//   Everything else byte-identical to R19 (stride-544, 16-tile K-loop +
//   rank-1 k=512 epilogue, cell hnew, tiled hbias, gemm2 col-512 fusion).
// ---------------------------------------------------------------------------

typedef __bf16 bf16x8 __attribute__((ext_vector_type(8)));
typedef float f32x4 __attribute__((ext_vector_type(4)));

#define MFMA_BF16 __builtin_amdgcn_mfma_f32_16x16x32_bf16

__device__ __forceinline__ void gld16(const void* gptr, void* lptr) {
  __builtin_amdgcn_global_load_lds(
      (const __attribute__((address_space(1))) void*)gptr,
      (__attribute__((address_space(3))) void*)lptr, 16, 0, 0);
}

// fast sigmoid: 1 exp + 1 raw rcp. x->-inf: exp->inf, rcp->0 (exact limit).
__device__ __forceinline__ float fsigm(float x) {
  return __builtin_amdgcn_rcpf(1.f + __expf(-x));
}
// fast tanh: 1 - 2*rcp(e^{2x}+1). x->+inf: rcp->0 -> 1; x->-inf: -> -1.
__device__ __forceinline__ float ftanh(float x) {
  return 1.f - 2.f * __builtin_amdgcn_rcpf(__expf(2.f * x) + 1.f);
}

// --------------------------- fused prep -------------------------------------
// Roles by blockIdx.x (long-running hbias first):
//   [0, 256)         hbias tiled: block owns 8 g; 8 Whh rows in LDS; loops 64 b
//   [256, 2304)      pack_wih (cols 0..511 -> wpk stride 544; col512 -> w512f)
//   [2304, 2944)     pack_fcw (rows 0..639, K 512, >=513 zero)
//   [2944, 68480)    pack_x (cols 0..511 -> xbf stride 544; col512 -> x512f)
__global__ __launch_bounds__(256) void prep_kernel(
    const float* __restrict__ x, const float* __restrict__ Wih,
    const float* __restrict__ fcw, const float* __restrict__ h0,
    const float* __restrict__ Whh, const float* __restrict__ bih,
    const float* __restrict__ bhh, __bf16* __restrict__ xbf,
    __bf16* __restrict__ wpk, __bf16* __restrict__ fwbf,
    float* __restrict__ hbias, float* __restrict__ w512f,
    float* __restrict__ x512f) {
  __shared__ float wsm[8][512];  // 16KB; only the hbias role touches it
  const int bid = blockIdx.x;
  const int t = threadIdx.x;

  if (bid < 256) {  // ---- hbias (tiled GEMV, f32-exact)
    const int g0 = bid * 8;
    for (int i = t; i < 8 * 512; i += 256)
      wsm[i >> 9][i & 511] = Whh[(size_t)(g0 + (i >> 9)) * 512 + (i & 511)];
    __syncthreads();
    const int g = t >> 5;   // 0..7
    const int kg = t & 31;  // 0..31
    const float bsum = bih[g0 + g] + bhh[g0 + g];
    for (int b = 0; b < 64; ++b) {
      const float* hr = h0 + b * 512 + kg;
      float s = 0.f;
#pragma unroll
      for (int q = 0; q < 16; ++q)
        s = fmaf(hr[32 * q], wsm[g][kg + 32 * q], s);
#pragma unroll
      for (int off = 16; off; off >>= 1) s += __shfl_down(s, off, 32);
      if (kg == 0) hbias[b * 2048 + g0 + g] = s + bsum;
    }
  } else if (bid < 2304) {  // ---- pack_wih
    const int p = bid - 256;
    const int g = (p >> 4) & 3;
    const int h = ((p >> 6) << 4) + (p & 15);
    const float* src = Wih + (size_t)(g * 512 + h) * 513;
    const int c = t * 2;  // 0..510
    union { __bf16 hh[2]; uint32_t u; } pk;
    pk.hh[0] = (__bf16)src[c];
    pk.hh[1] = (__bf16)src[c + 1];
    *(uint32_t*)&wpk[(size_t)p * 544 + c] = pk.u;
    if (t == 0) w512f[p] = src[512];
  } else if (bid < 2944) {  // ---- pack_fcw
    const int r = bid - 2304;
    const bool rv = r < 513;
    const float* src = fcw + (size_t)r * 512;
    const int c = t * 2;
    union { __bf16 hh[2]; uint32_t u; } pk;
    pk.hh[0] = (__bf16)(rv ? src[c] : 0.f);
    pk.hh[1] = (__bf16)(rv ? src[c + 1] : 0.f);
    *(uint32_t*)&fwbf[(size_t)r * 512 + c] = pk.u;
  } else {  // ---- pack_x
    const int r = bid - 2944;
    const float* src = x + (size_t)r * 513;
    const int c = t * 2;  // 0..510
    union { __bf16 hh[2]; uint32_t u; } pk;
    pk.hh[0] = (__bf16)src[c];
    pk.hh[1] = (__bf16)src[c + 1];
    *(uint32_t*)&xbf[(size_t)r * 544 + c] = pk.u;
    if (t == 0) x512f[r] = src[512];
  }
}

// --------------------------- R4 core: 128x128, 4 waves ----------------------
// LDS: 3 buffers x (A 8KB + B 8KB) = 48KB. One barrier + vmcnt(4)/K-tile.
template <int NKT, int KSTR>
__device__ __forceinline__ void gemm_core4(
    const __bf16* __restrict__ A, const __bf16* __restrict__ B,
    size_t m0, int n0, char* lds, f32x4 (&acc)[4][4],
    int w, int l, int wm, int wc) {
  const int lr = l & 15, lq = l >> 4;
  const __bf16* ag = A + (m0 + w * 32 + lr) * KSTR + lq * 8;
  const __bf16* bg = B + (size_t)(n0 + w * 32 + lr) * KSTR + lq * 8;
  const int sdst = w * 2048;
  const int ra = wm * 4096 + l * 16;
  const int rbB = 8192 + wc * 4096 + l * 16;

#pragma unroll
  for (int p = 0; p < 2; ++p) {
    char* base = lds + p * 16384;
    gld16(ag + p * 32, base + sdst);
    gld16(ag + p * 32 + 16 * KSTR, base + sdst + 1024);
    gld16(bg + p * 32, base + 8192 + sdst);
    gld16(bg + p * 32 + 16 * KSTR, base + 8192 + sdst + 1024);
  }
  asm volatile("s_waitcnt vmcnt(4)" ::: "memory");
  __builtin_amdgcn_s_barrier();

  int rb = 0;
  for (int kt = 0; kt < NKT; ++kt) {
    char* rbase = lds + rb * 16384;
    if (kt + 2 < NKT) {
      char* wbase = lds + ((rb + 2) % 3) * 16384;
      const int kof = (kt + 2) * 32;
      gld16(ag + kof, wbase + sdst);
      gld16(ag + kof + 16 * KSTR, wbase + sdst + 1024);
      gld16(bg + kof, wbase + 8192 + sdst);
      gld16(bg + kof + 16 * KSTR, wbase + 8192 + sdst + 1024);
    }
    bf16x8 af[4], bq[4];
#pragma unroll
    for (int i = 0; i < 4; ++i)
      af[i] = *(const bf16x8*)(rbase + ra + i * 1024);
#pragma unroll
    for (int i = 0; i < 4; ++i)
      bq[i] = *(const bf16x8*)(rbase + rbB + i * 1024);
    __builtin_amdgcn_s_setprio(1);
#pragma unroll
    for (int mi = 0; mi < 4; ++mi)
#pragma unroll
      for (int ni = 0; ni < 4; ++ni)
        acc[mi][ni] = MFMA_BF16(af[mi], bq[ni], acc[mi][ni], 0, 0, 0);
    __builtin_amdgcn_s_setprio(0);
    if (kt + 2 < NKT) {
      asm volatile("s_waitcnt vmcnt(4)" ::: "memory");
    } else if (kt + 1 < NKT) {
      asm volatile("s_waitcnt vmcnt(0)" ::: "memory");
    }
    asm volatile("" ::: "memory");
    __builtin_amdgcn_s_barrier();
    rb = (rb == 2) ? 0 : rb + 1;
  }
}

// --------------------------- GEMM1 + LSTM cell ------------------------------
// A = xbf [65536 x 544-stride], B = wpk [2048 x 544-stride], K = 512
// (16 tiles); k=512 added in the epilogue as a rank-1 f32 update.
// Output: hnew CELLS [4096 sm][16 kc] x 1KB; cell: lane=(kq<<4)|row, 8 k.
__global__ __launch_bounds__(256, 3) void gemm1_kernel(
    const __bf16* __restrict__ xbf, const __bf16* __restrict__ wpk,
    const float* __restrict__ hbias, const float* __restrict__ c0,
    const float* __restrict__ w512f, const float* __restrict__ x512f,
    __bf16* __restrict__ hnew) {
  const int t = threadIdx.x, w = t >> 6, l = t & 63;
  const int wm = w >> 1, wc = w & 1;
  const int bid = blockIdx.x;
  const int swz = (bid & 7) * 1024 + (bid >> 3);  // XCD-contiguous
  const size_t m0 = (size_t)(swz >> 4) << 7;
  const int n0 = (swz & 15) << 7;

  __shared__ __align__(16) char lds[49152];

  f32x4 acc[4][4];
#pragma unroll
  for (int mi = 0; mi < 4; ++mi)
#pragma unroll
    for (int ni = 0; ni < 4; ++ni) acc[mi][ni] = (f32x4){0.f, 0.f, 0.f, 0.f};

  gemm_core4<16, 544>(xbf, wpk, m0, n0, lds, acc, w, l, wm, wc);

  // lane's packed col p = n0 + wc*64 + ni*16 + lr -> gate = ni,
  // hcol = ((n0>>6)+wc)*16 + lr. All 4 gates lane-local.
  const int lr = l & 15, lq = l >> 4;
  const int hcol = (((n0 >> 6) + wc) << 4) + lr;
  const int b = (int)(m0 >> 10);
  const float hb0 = hbias[b * 2048 + hcol];
  const float hb1 = hbias[b * 2048 + 512 + hcol];
  const float hb2 = hbias[b * 2048 + 1024 + hcol];
  const float hb3 = hbias[b * 2048 + 1536 + hcol];
  const float c0v = c0[b * 512 + hcol];
  // k=512 rank-1 weights for this lane's 4 packed cols (gate = ni)
  const int pbase = n0 + wc * 64 + lr;
  const float w5_0 = w512f[pbase];
  const float w5_1 = w512f[pbase + 16];
  const float w5_2 = w512f[pbase + 32];
  const float w5_3 = w512f[pbase + 48];
  char* stg = lds;  // K-loop done (loop ends with barrier): LDS free
  const int l2b = (wc * 2 + (lr >> 3)) << 4;
  const int byt = (lr & 7) * 2;
#pragma unroll
  for (int mi = 0; mi < 4; ++mi) {
    // 4 consecutive m-rows (r = 0..3): one vectorized x512f load
    const f32x4 xv4 = *(const f32x4*)&x512f[m0 + wm * 64 + mi * 16 + lq * 4];
#pragma unroll
    for (int r = 0; r < 4; ++r) {
      const float xv = xv4[r];
      const float gi = acc[mi][0][r] + hb0 + xv * w5_0;
      const float gf = acc[mi][1][r] + hb1 + xv * w5_1;
      const float gg = acc[mi][2][r] + hb2 + xv * w5_2;
      const float go = acc[mi][3][r] + hb3 + xv * w5_3;
      const float cn = fsigm(gf) * c0v + fsigm(gi) * ftanh(gg);
      const float hv = fsigm(go) * ftanh(cn);
      *(__bf16*)(stg + ((wm * 4 + mi) << 10) + (l2b + lq * 4 + r) * 16 + byt) =
          (__bf16)hv;
    }
  }
  __syncthreads();
  const int kc = n0 >> 7;
  char* hnc = (char*)hnew;
#pragma unroll
  for (int p = 0; p < 2; ++p) {
    const int cl = p * 4 + (t >> 6);
    const uint4 v = *(const uint4*)(stg + cl * 1024 + (t & 63) * 16);
    *(uint4*)(hnc + ((((m0 >> 4) + cl) << 4) + kc) * 1024 + (t & 63) * 16) = v;
  }
}

// --------------------------- R7 core, A from cells + col-512 fusion ---------
template <int NKT>
__device__ __forceinline__ void gemm_core8f(
    const char* __restrict__ Ac, const __bf16* __restrict__ B,
    size_t m0, int n0, char* lds, f32x4 (&acc)[4][4], float (&acc512)[4],
    bool do512, int wid, int l, int wm, int wc) {
  const int lr = l & 15, lq = l >> 4;
  const char* ag = Ac + (((m0 >> 4) + wid) << 14) + l * 16;   // subtile wid
  const char* ag2 = ag + (size_t)(8 << 14);                   // +128 rows
  const __bf16* bg = B + (size_t)(n0 + wid * 16 + lr) * 512 + lq * 8;
  const __bf16* w512p = B + (size_t)512 * 512 + lq * 8;       // fcw row 512
  const int sdA = wid << 10;
  const int sdB = 16384 + (wid << 10);
  const int ra = (wm << 12) + l * 16;
  const int rbB = 16384 + (wc << 12) + l * 16;

#pragma unroll
  for (int p = 0; p < 2; ++p) {
    char* base = lds + p * 24576;
    gld16(ag + p * 1024, base + sdA);
    gld16(ag2 + p * 1024, base + sdA + 8192);
    gld16(bg + p * 32, base + sdB);
  }
  asm volatile("s_waitcnt vmcnt(3)" ::: "memory");
  __builtin_amdgcn_s_barrier();

#pragma unroll
  for (int kt = 0; kt < NKT; ++kt) {
    char* rbase = lds + (kt % 3) * 24576;
    if (kt + 2 < NKT) {
      char* wbase = lds + ((kt + 2) % 3) * 24576;
      gld16(ag + (kt + 2) * 1024, wbase + sdA);
      gld16(ag2 + (kt + 2) * 1024, wbase + sdA + 8192);
      gld16(bg + (kt + 2) * 32, wbase + sdB);
    }
    bf16x8 af[4], bq[4];
#pragma unroll
    for (int i = 0; i < 4; ++i)
      af[i] = *(const bf16x8*)(rbase + ra + i * 1024);
#pragma unroll
    for (int i = 0; i < 4; ++i)
      bq[i] = *(const bf16x8*)(rbase + rbB + i * 1024);
    if (do512) {  // block- and wave-uniform branch
      const bf16x8 wv = *(const bf16x8*)(w512p + kt * 32);
#pragma unroll
      for (int mi = 0; mi < 4; ++mi)
#pragma unroll
        for (int j = 0; j < 8; ++j)
          acc512[mi] = fmaf((float)af[mi][j], (float)wv[j], acc512[mi]);
    }
    __builtin_amdgcn_s_setprio(1);
#pragma unroll
    for (int mi = 0; mi < 4; ++mi)
#pragma unroll
      for (int ni = 0; ni < 4; ++ni)
        acc[mi][ni] = MFMA_BF16(af[mi], bq[ni], acc[mi][ni], 0, 0, 0);
    __builtin_amdgcn_s_setprio(0);
    if (kt + 2 < NKT) {
      asm volatile("s_waitcnt vmcnt(3)" ::: "memory");
    } else if (kt + 1 < NKT) {
      asm volatile("s_waitcnt vmcnt(0)" ::: "memory");
    }
    asm volatile("" ::: "memory");
    __builtin_amdgcn_s_barrier();
  }
}

// --------------------------- GEMM2 + bias -----------------------------------
// A = hnew cells, B = fwbf. grid 1024 = 256 m-tiles x 4 n-tiles (cols 0..511).
// Col n=512 computed by ntile-0 blocks via the fused side-accumulation.
__global__ __launch_bounds__(512, 4) void gemm2_kernel(
    const char* __restrict__ hnc, const __bf16* __restrict__ fcw,
    const float* __restrict__ fcb, float* __restrict__ out) {
  const int t = threadIdx.x, wid = t >> 6, l = t & 63;
  const int wm = wid >> 1, wc = wid & 1;
  const int bid = blockIdx.x;
  const int swz = (bid & 7) * 128 + (bid >> 3);   // 1024 blocks
  const size_t m0 = (size_t)(swz >> 2) << 8;
  const int ntile = swz & 3;
  const int n0 = ntile << 7;
  const bool do512 = (ntile == 0) && (wc == 0);

  __shared__ __align__(16) char lds[73728];

  f32x4 acc[4][4];
  float acc512[4] = {0.f, 0.f, 0.f, 0.f};
#pragma unroll
  for (int mi = 0; mi < 4; ++mi)
#pragma unroll
    for (int ni = 0; ni < 4; ++ni) acc[mi][ni] = (f32x4){0.f, 0.f, 0.f, 0.f};

  gemm_core8f<16>(hnc, fcw, m0, n0, lds, acc, acc512, do512, wid, l, wm, wc);

  const int lr = l & 15, lq = l >> 4;
#pragma unroll
  for (int ni = 0; ni < 4; ++ni) {
    const int n = n0 + wc * 64 + ni * 16 + lr;
    const float bias = fcb[n];
#pragma unroll
    for (int mi = 0; mi < 4; ++mi) {
#pragma unroll
      for (int r = 0; r < 4; ++r) {
        const size_t m = m0 + wm * 64 + mi * 16 + lq * 4 + r;
        out[m * 513 + n] = acc[mi][ni][r] + bias;
      }
    }
  }
  if (do512) {  // reduce k-slices (lanes lr, 16+lr, 32+lr, 48+lr) and store
    const float b512 = fcb[512];
#pragma unroll
    for (int mi = 0; mi < 4; ++mi) {
      float s = acc512[mi];
      s += __shfl_down(s, 32);
      s += __shfl_down(s, 16);
      if (lq == 0) {
        const size_t m = m0 + (wm * 4 + mi) * 16 + lr;
        out[m * 513 + 512] = s + b512;
      }
    }
  }
}

// --------------------------- launch -----------------------------------------
extern "C" void kernel_launch(void* const* d_in, const int* in_sizes, int n_in,
                              void* d_out, int out_size, void* d_ws, size_t ws_size,
                              hipStream_t stream) {
  const float* x = (const float*)d_in[0];     // [64,1024,513]
  const float* h0 = (const float*)d_in[1];    // [1,64,512]
  const float* c0 = (const float*)d_in[2];    // [1,64,512]
  const float* Wih = (const float*)d_in[3];   // [2048,513]
  const float* Whh = (const float*)d_in[4];   // [2048,512]
  const float* bih = (const float*)d_in[5];   // [2048]
  const float* bhh = (const float*)d_in[6];   // [2048]
  const float* fcw = (const float*)d_in[7];   // [513,512]
  const float* fcb = (const float*)d_in[8];   // [513]
  float* out = (float*)d_out;                 // [64,1024,513]

  char* ws = (char*)d_ws;
  __bf16* xbf = (__bf16*)(ws);                 // 65536*544*2 = 71,303,168
  __bf16* wpk = (__bf16*)(ws + 71303168);      //  2048*544*2 =  2,228,224
  float* w512f = (float*)(ws + 73531392);      //      2048*4 =      8,192
  __bf16* fwbf = (__bf16*)(ws + 73539584);     //   640*512*2 =    655,360
  float* hb = (float*)(ws + 74194944);         //   64*2048*4 =    524,288
  float* x512f = (float*)(ws + 74719232);      //     65536*4 =    262,144
  char* hn = ws + 74981376;                    // cells: 4096*16*1024 = 67,108,864
  // total ws use: 142,090,240 bytes

  prep_kernel<<<68480, 256, 0, stream>>>(x, Wih, fcw, h0, Whh, bih, bhh,
                                         xbf, wpk, fwbf, hb, w512f, x512f);
  gemm1_kernel<<<8192, 256, 0, stream>>>(xbf, wpk, hb, c0, w512f, x512f,
                                         (__bf16*)hn);
  gemm2_kernel<<<1024, 512, 0, stream>>>(hn, fwbf, fcb, out);
}